// Round 1
// 508.253 us; speedup vs baseline: 1.1261x; 1.1261x over previous
//
#include <hip/hip_runtime.h>
#include <hip/hip_fp16.h>
#include <math.h>

#define N_NODES 200000
#define N_EDGES 6400000
#define T 6
#define M 10

// CSR build configuration: 256-node buckets, chunked counting sort.
// NBLK=256 / CH=25000: exactly 1 block per CU (256 CUs), 16 waves/CU,
// perfectly balanced; mean segment per (bucket,chunk) = 32 edges = 128 B
// = one TCC line (was 196 blocks -> 60 idle CUs, 8 waves/CU, 168 B frags).
#define NB    782            // ceil(200000/256) buckets (dst>>8)
#define NBLK  256            // edge chunks == CU count
#define CH    25000          // edges per chunk (256*25000 = 6.4M exact)
#define GHLEN (NB * NBLK)    // 200192
#define CAP   14336          // max edges per bucket (mean 8186, sigma 90 -> 68 sigma margin)

#define SBLOCKS 196          // ceil(GHLEN/1024) scan blocks

typedef __attribute__((ext_vector_type(2))) float vf2;
typedef __attribute__((ext_vector_type(4))) unsigned int u32x4;

// ---------------------------------------------------------------------------
// convert x_member [N,6] fp32 -> xh [N,8] fp16 (zero-padded), 16 B rows.
// NT loads (read-once) + NT store (coalesced write-once: safe).
// ---------------------------------------------------------------------------
__global__ __launch_bounds__(256) void convert_kernel(
    const float* __restrict__ x, __half* __restrict__ xh)
{
    int i = blockIdx.x * 256 + threadIdx.x;
    if (i >= N_NODES) return;
    const vf2* p = (const vf2*)(x + (size_t)i * 6);   // rows 24B -> 8B aligned
    vf2 a = __builtin_nontemporal_load(p);
    vf2 b = __builtin_nontemporal_load(p + 1);
    vf2 c = __builtin_nontemporal_load(p + 2);
    union { __half2 h[4]; u32x4 q; } u;
    u.h[0] = __floats2half2_rn(a.x, a.y);
    u.h[1] = __floats2half2_rn(b.x, b.y);
    u.h[2] = __floats2half2_rn(c.x, c.y);
    u.h[3] = __floats2half2_rn(0.f, 0.f);
    __builtin_nontemporal_store(u.q, (u32x4*)(xh + (size_t)i * 8));
}

// ---------------------------------------------------------------------------
// Pass A: per-chunk bucket histogram -> gh[bucket*NBLK + chunk]
// 1024 threads: 16 waves/CU, one block per CU.
// ---------------------------------------------------------------------------
__global__ __launch_bounds__(1024) void passA_kernel(
    const int* __restrict__ dst, int* __restrict__ gh)
{
    __shared__ int lh[NB];
    int g = blockIdx.x;
    for (int t = threadIdx.x; t < NB; t += 1024) lh[t] = 0;
    __syncthreads();
    int base = g * CH;
    int end  = base + CH; if (end > N_EDGES) end = N_EDGES;
    for (int e = base + threadIdx.x; e < end; e += 1024)
        atomicAdd(&lh[__builtin_nontemporal_load(dst + e) >> 8], 1);
    __syncthreads();
    for (int t = threadIdx.x; t < NB; t += 1024) gh[t * NBLK + g] = lh[t];
}

// ---------------------------------------------------------------------------
// Hierarchical exclusive scan of gh[GHLEN]
// ---------------------------------------------------------------------------
__global__ __launch_bounds__(1024) void scan1_kernel(
    int* __restrict__ gh, int* __restrict__ bsum)
{
    __shared__ int sbuf[1024];
    int tid = threadIdx.x;
    int t   = blockIdx.x * 1024 + tid;
    int v   = (t < GHLEN) ? gh[t] : 0;
    sbuf[tid] = v;
    __syncthreads();
    for (int d = 1; d < 1024; d <<= 1) {
        int u = (tid >= d) ? sbuf[tid - d] : 0;
        __syncthreads();
        sbuf[tid] += u;
        __syncthreads();
    }
    if (t < GHLEN) gh[t] = sbuf[tid] - v;           // local exclusive
    if (tid == 1023) bsum[blockIdx.x] = sbuf[1023]; // block total
}

__global__ __launch_bounds__(256) void scan2_kernel(int* __restrict__ bsum)
{
    __shared__ int sbuf[256];
    int tid = threadIdx.x;
    int v = (tid < SBLOCKS) ? bsum[tid] : 0;
    sbuf[tid] = v;
    __syncthreads();
    for (int d = 1; d < 256; d <<= 1) {
        int u = (tid >= d) ? sbuf[tid - d] : 0;
        __syncthreads();
        sbuf[tid] += u;
        __syncthreads();
    }
    if (tid < SBLOCKS) bsum[tid] = sbuf[tid] - v;   // exclusive
}

__global__ __launch_bounds__(1024) void scan3_kernel(
    int* __restrict__ gh, const int* __restrict__ bsum)
{
    int t = blockIdx.x * 1024 + threadIdx.x;
    if (t < GHLEN) gh[t] += bsum[blockIdx.x];
}

// ---------------------------------------------------------------------------
// Pass C: place edges into bucket-grouped ebuf via LDS cursors (no global
// atomics). ebuf[pos] = (src<<8) | (dst & 255). Scattered stores go through
// L2 (normal stores) so they coalesce before eviction.
// 1024 threads / 256 blocks: every CU active at 16 waves (was 196 blocks ->
// 60 CUs idle, 8 waves). Latency-bound loop (NT load -> LDS atomic ->
// divergent store); wave count is the only hiding lever.
// ---------------------------------------------------------------------------
__global__ __launch_bounds__(1024) void passC_kernel(
    const int* __restrict__ src, const int* __restrict__ dst,
    const int* __restrict__ gh, int* __restrict__ ebuf)
{
    __shared__ int lcur[NB];
    int g = blockIdx.x;
    for (int t = threadIdx.x; t < NB; t += 1024) lcur[t] = gh[t * NBLK + g];
    __syncthreads();
    int base = g * CH;
    int end  = base + CH; if (end > N_EDGES) end = N_EDGES;
    for (int e = base + threadIdx.x; e < end; e += 1024) {
        int s = __builtin_nontemporal_load(src + e);
        int d = __builtin_nontemporal_load(dst + e);
        int p = atomicAdd(&lcur[d >> 8], 1);    // LDS atomic
        ebuf[p] = (s << 8) | (d & 255);
    }
}

// ---------------------------------------------------------------------------
// Pass D: per-bucket counting sort, IN PLACE (col aliases ebuf).
// Scatter store is a NORMAL store: NT scatter stores bypass L2 write-
// combining and cost 8x write amplification at HBM (measured R7: 259 MB
// WRITE for 26 MB payload). L2 absorbs+coalesces the 32 KB bucket range.
// ---------------------------------------------------------------------------
__global__ __launch_bounds__(256) void passD_kernel(
    const int* __restrict__ gh, int* __restrict__ col, int* __restrict__ off)
{
    __shared__ int earr[CAP];
    __shared__ int hist[256];
    __shared__ int incl[256];
    int b = blockIdx.x;
    int ebase = gh[b * NBLK];
    int eend  = (b == NB - 1) ? N_EDGES : gh[(b + 1) * NBLK];
    int n = eend - ebase;
    if (n > CAP) n = CAP;   // 68-sigma margin; never triggers for this input
    for (int k = threadIdx.x; k < n; k += 256)
        earr[k] = __builtin_nontemporal_load(col + ebase + k);
    hist[threadIdx.x] = 0;
    __syncthreads();
    for (int k = threadIdx.x; k < n; k += 256) atomicAdd(&hist[earr[k] & 255], 1);
    __syncthreads();
    int t = threadIdx.x;
    int h = hist[t];
    incl[t] = h;
    __syncthreads();
    for (int d = 1; d < 256; d <<= 1) {
        int v = (t >= d) ? incl[t - d] : 0;
        __syncthreads();
        incl[t] += v;
        __syncthreads();
    }
    int node = b * 256 + t;
    if (node < N_NODES) off[node] = ebase + incl[t];
    hist[t] = incl[t] - h;                       // exclusive cursor
    __syncthreads();
    for (int k = threadIdx.x; k < n; k += 256) {
        int e = earr[k];
        int p = atomicAdd(&hist[e & 255], 1);    // LDS atomic
        col[ebase + p] = e >> 8;                 // normal store (L2 coalesces)
    }
}

// ---------------------------------------------------------------------------
// round: v = in[i] + sum_{j in CSR(i)} in[col[j]]; rout[i] = sigmoid(v @ H)
// stored fp8 e4m3 (16 B rows -> 3.2 MB gather table).
// col/off reads NT (stream, don't evict the gather table from L2);
// rout store NT (coalesced write-once).
// Grid supplies only ~3 waves/SIMD (782 blocks x 4 waves / 256 CU), so
// per-lane MLP is the latency-hiding lever: 8 outstanding gathers/lane.
// ---------------------------------------------------------------------------
template<int TD, bool FP8IN>
__device__ inline void accum_row(u32x4 q, float* v)
{
    if (FP8IN) {
        vf2 f0 = __builtin_amdgcn_cvt_pk_f32_fp8(q.x, false);
        vf2 f1 = __builtin_amdgcn_cvt_pk_f32_fp8(q.x, true);
        vf2 f2 = __builtin_amdgcn_cvt_pk_f32_fp8(q.y, false);
        vf2 f3 = __builtin_amdgcn_cvt_pk_f32_fp8(q.y, true);
        vf2 f4 = __builtin_amdgcn_cvt_pk_f32_fp8(q.z, false);
        v[0] += f0.x; v[1] += f0.y; v[2] += f1.x; v[3] += f1.y;
        v[4] += f2.x; v[5] += f2.y; v[6] += f3.x; v[7] += f3.y;
        v[8] += f4.x; v[9] += f4.y;
    } else {
        union { u32x4 q; __half2 h[8]; } u; u.q = q;
#pragma unroll
        for (int k = 0; k < TD / 2; ++k) {
            float2 f = __half22float2(u.h[k]);
            v[2 * k] += f.x; v[2 * k + 1] += f.y;
        }
    }
}

template<int TD, bool FP8IN>
__global__ __launch_bounds__(256) void round_kernel(
    const u32x4* __restrict__ in,      // [N] 16 B rows (fp16x8 or fp8x16)
    const int*   __restrict__ off,
    const int*   __restrict__ col,
    u32x4*       __restrict__ rout,    // [N] 16 B fp8 rows
    const float* __restrict__ H,       // [TD, M]
    const float* __restrict__ Wsc, int widx,
    float*       __restrict__ facc)
{
    int i = blockIdx.x * 256 + threadIdx.x;
    float w = Wsc[widx];
    float sm[M];

    if (i < N_NODES) {
        float v[TD];
#pragma unroll
        for (int t = 0; t < TD; ++t) v[t] = 0.0f;
        accum_row<TD, FP8IN>(in[i], v);
        int start = (i == 0) ? 0 : __builtin_nontemporal_load(off + i - 1);
        int end   = __builtin_nontemporal_load(off + i);

        int j = start;
        for (; j + 8 <= end; j += 8) {           // 8 outstanding gathers/lane
            int s0 = __builtin_nontemporal_load(col + j);
            int s1 = __builtin_nontemporal_load(col + j + 1);
            int s2 = __builtin_nontemporal_load(col + j + 2);
            int s3 = __builtin_nontemporal_load(col + j + 3);
            int s4 = __builtin_nontemporal_load(col + j + 4);
            int s5 = __builtin_nontemporal_load(col + j + 5);
            int s6 = __builtin_nontemporal_load(col + j + 6);
            int s7 = __builtin_nontemporal_load(col + j + 7);
            u32x4 q0 = in[s0], q1 = in[s1], q2 = in[s2], q3 = in[s3];
            u32x4 q4 = in[s4], q5 = in[s5], q6 = in[s6], q7 = in[s7];
            accum_row<TD, FP8IN>(q0, v);
            accum_row<TD, FP8IN>(q1, v);
            accum_row<TD, FP8IN>(q2, v);
            accum_row<TD, FP8IN>(q3, v);
            accum_row<TD, FP8IN>(q4, v);
            accum_row<TD, FP8IN>(q5, v);
            accum_row<TD, FP8IN>(q6, v);
            accum_row<TD, FP8IN>(q7, v);
        }
        for (; j + 4 <= end; j += 4) {
            int s0 = __builtin_nontemporal_load(col + j);
            int s1 = __builtin_nontemporal_load(col + j + 1);
            int s2 = __builtin_nontemporal_load(col + j + 2);
            int s3 = __builtin_nontemporal_load(col + j + 3);
            u32x4 q0 = in[s0], q1 = in[s1], q2 = in[s2], q3 = in[s3];
            accum_row<TD, FP8IN>(q0, v);
            accum_row<TD, FP8IN>(q1, v);
            accum_row<TD, FP8IN>(q2, v);
            accum_row<TD, FP8IN>(q3, v);
        }
        for (; j < end; ++j)
            accum_row<TD, FP8IN>(in[__builtin_nontemporal_load(col + j)], v);

        float z[M];
#pragma unroll
        for (int m = 0; m < M; ++m) {
            float acc = 0.0f;
#pragma unroll
            for (int t = 0; t < TD; ++t) acc += v[t] * H[t * M + m];
            z[m] = acc;
        }
        float rr[M];
        float ssum = 0.0f;
#pragma unroll
        for (int m = 0; m < M; ++m) {
            rr[m] = 1.0f / (1.0f + __expf(-z[m]));
            sm[m] = __expf(rr[m] * w);            // rr*w in (0,0.2): no max shift
            ssum += sm[m];
        }
        {
            int d0 = __builtin_amdgcn_cvt_pk_fp8_f32(rr[0], rr[1], 0, false);
            d0     = __builtin_amdgcn_cvt_pk_fp8_f32(rr[2], rr[3], d0, true);
            int d1 = __builtin_amdgcn_cvt_pk_fp8_f32(rr[4], rr[5], 0, false);
            d1     = __builtin_amdgcn_cvt_pk_fp8_f32(rr[6], rr[7], d1, true);
            int d2 = __builtin_amdgcn_cvt_pk_fp8_f32(rr[8], rr[9], 0, false);
            u32x4 o = { (unsigned)d0, (unsigned)d1, (unsigned)d2, 0u };
            __builtin_nontemporal_store(o, rout + i);
        }
        float inv = 1.0f / ssum;
#pragma unroll
        for (int m = 0; m < M; ++m) sm[m] *= inv;
    } else {
#pragma unroll
        for (int m = 0; m < M; ++m) sm[m] = 0.0f;
    }

    // wave-64 shuffle reduction of the 10 softmax sums
#pragma unroll
    for (int m = 0; m < M; ++m) {
        float x = sm[m];
#pragma unroll
        for (int o = 32; o > 0; o >>= 1) x += __shfl_down(x, o);
        sm[m] = x;
    }
    __shared__ float ls[4][M];
    int lane = threadIdx.x & 63;
    int wv   = threadIdx.x >> 6;
    if (lane == 0) {
#pragma unroll
        for (int m = 0; m < M; ++m) ls[wv][m] = sm[m];
    }
    __syncthreads();
    if (threadIdx.x < M) {
        float a = ls[0][threadIdx.x] + ls[1][threadIdx.x]
                + ls[2][threadIdx.x] + ls[3][threadIdx.x];
        atomicAdd(&facc[threadIdx.x], a);
    }
}

// ---------------------------------------------------------------------------
// final head: out[3] = concat(f[10], x_group@Wg[4]) @ Wm
// ---------------------------------------------------------------------------
__global__ void final_kernel(const float* __restrict__ facc,
                             const float* __restrict__ xg,
                             const float* __restrict__ Wg,
                             const float* __restrict__ Wm,
                             float* __restrict__ out)
{
    if (threadIdx.x == 0 && blockIdx.x == 0) {
        float go[4];
        for (int g = 0; g < 4; ++g) {
            float a = 0.0f;
            for (int i = 0; i < 14; ++i) a += xg[i] * Wg[i * 4 + g];
            go[g] = a;
        }
        for (int j = 0; j < 3; ++j) {
            float o = 0.0f;
            for (int k = 0; k < M; ++k) o += facc[k] * Wm[k * 3 + j];
            for (int g = 0; g < 4; ++g)  o += go[g] * Wm[(M + g) * 3 + j];
            out[j] = o;
        }
    }
}

extern "C" void kernel_launch(void* const* d_in, const int* in_sizes, int n_in,
                              void* d_out, int out_size, void* d_ws, size_t ws_size,
                              hipStream_t stream)
{
    const float* x_member = (const float*)d_in[0];
    const float* x_group  = (const float*)d_in[1];
    const int*   edge_src = (const int*)  d_in[2];
    const int*   edge_dst = (const int*)  d_in[3];
    const float* H0       = (const float*)d_in[4];
    const float* Hs       = (const float*)d_in[5];
    const float* Wsc      = (const float*)d_in[6];
    const float* Wg       = (const float*)d_in[7];
    const float* Wm       = (const float*)d_in[8];
    float* out = (float*)d_out;

    // workspace layout — 36.8 MB:
    //   col/ebuf : 25,600,000 B   (in-place counting sort)
    //   off      :    800,000 B
    //   xh       :  3,200,000 B   [N] fp16x8, 16 B rows
    //   r0b      :  3,200,000 B   [N] fp8x16, 16 B rows
    //   r1b      :  3,200,000 B   [N] fp8x16 (gh[GHLEN]+bsum alias its head:
    //              dead after passD; r1b first written in round 1)
    //   facc     :         64 B
    char* w = (char*)d_ws;
    int*    col  = (int*)w;
    int*    off  = (int*)(w + 25600000);
    __half* xh   = (__half*)(w + 26400000);
    u32x4*  r0b  = (u32x4*)(w + 29600000);
    u32x4*  r1b  = (u32x4*)(w + 32800000);
    int*    gh   = (int*)(w + 32800000);          // aliases r1b
    int*    bsum = gh + GHLEN;                    // also in r1b region
    float*  facc = (float*)(w + 36000000);

    (void)hipMemsetAsync(facc, 0, 64, stream);

    const int nblocks = (N_NODES + 255) / 256;    // 782

    convert_kernel<<<nblocks, 256, 0, stream>>>(x_member, xh);
    passA_kernel<<<NBLK, 1024, 0, stream>>>(edge_dst, gh);
    scan1_kernel<<<SBLOCKS, 1024, 0, stream>>>(gh, bsum);
    scan2_kernel<<<1, 256, 0, stream>>>(bsum);
    scan3_kernel<<<SBLOCKS, 1024, 0, stream>>>(gh, bsum);
    passC_kernel<<<NBLK, 1024, 0, stream>>>(edge_src, edge_dst, gh, col);
    passD_kernel<<<NB, 256, 0, stream>>>(gh, col, off);

    round_kernel<T, false><<<nblocks, 256, 0, stream>>>((const u32x4*)xh, off, col, r0b, H0,             Wsc, 0, facc);
    round_kernel<M, true ><<<nblocks, 256, 0, stream>>>(r0b,              off, col, r1b, Hs + 0 * M * M, Wsc, 1, facc);
    round_kernel<M, true ><<<nblocks, 256, 0, stream>>>(r1b,              off, col, r0b, Hs + 1 * M * M, Wsc, 2, facc);
    round_kernel<M, true ><<<nblocks, 256, 0, stream>>>(r0b,              off, col, r1b, Hs + 2 * M * M, Wsc, 3, facc);

    final_kernel<<<1, 64, 0, stream>>>(facc, x_group, Wg, Wm, out);
}

// Round 2
// 441.480 us; speedup vs baseline: 1.2965x; 1.1512x over previous
//
#include <hip/hip_runtime.h>
#include <hip/hip_fp16.h>
#include <math.h>

#define N_NODES 200000
#define N_EDGES 6400000
#define T 6
#define M 10

// CSR build configuration: 256-node buckets, chunked counting sort.
// NBLK=256 / CH=25000: exactly 1 block per CU (256 CUs), 16 waves/CU,
// perfectly balanced; mean segment per (bucket,chunk) = 32 edges = 128 B.
#define NB    782            // ceil(200000/256) buckets (dst>>8)
#define NBLK  256            // edge chunks == CU count
#define CH    25000          // edges per chunk (256*25000 = 6.4M exact)
#define GHLEN (NB * NBLK)    // 200192
#define CAP   14336          // max edges per bucket (mean 8186, sigma 90 -> 68 sigma margin)

#define SBLOCKS 196          // ceil(GHLEN/1024) scan blocks

// passC dynamic LDS: edge array (CH) + cnt/ls/lcur/gs (4*NB) + scan buf (1024)
#define PASSC_LDS_INTS  (CH + 4 * NB + 1024)
#define PASSC_LDS_BYTES (PASSC_LDS_INTS * 4)   // 116,608 B < 160 KiB/CU

typedef __attribute__((ext_vector_type(2))) float vf2;
typedef __attribute__((ext_vector_type(4))) unsigned int u32x4;

// ---------------------------------------------------------------------------
// convert x_member [N,6] fp32 -> xh [N,8] fp16 (zero-padded), 16 B rows.
// ---------------------------------------------------------------------------
__global__ __launch_bounds__(256) void convert_kernel(
    const float* __restrict__ x, __half* __restrict__ xh)
{
    int i = blockIdx.x * 256 + threadIdx.x;
    if (i >= N_NODES) return;
    const vf2* p = (const vf2*)(x + (size_t)i * 6);   // rows 24B -> 8B aligned
    vf2 a = __builtin_nontemporal_load(p);
    vf2 b = __builtin_nontemporal_load(p + 1);
    vf2 c = __builtin_nontemporal_load(p + 2);
    union { __half2 h[4]; u32x4 q; } u;
    u.h[0] = __floats2half2_rn(a.x, a.y);
    u.h[1] = __floats2half2_rn(b.x, b.y);
    u.h[2] = __floats2half2_rn(c.x, c.y);
    u.h[3] = __floats2half2_rn(0.f, 0.f);
    __builtin_nontemporal_store(u.q, (u32x4*)(xh + (size_t)i * 8));
}

// ---------------------------------------------------------------------------
// Pass A: per-chunk bucket histogram -> gh[bucket*NBLK + chunk]
// ---------------------------------------------------------------------------
__global__ __launch_bounds__(1024) void passA_kernel(
    const int* __restrict__ dst, int* __restrict__ gh)
{
    __shared__ int lh[NB];
    int g = blockIdx.x;
    for (int t = threadIdx.x; t < NB; t += 1024) lh[t] = 0;
    __syncthreads();
    int base = g * CH;
    int end  = base + CH; if (end > N_EDGES) end = N_EDGES;
    for (int e = base + threadIdx.x; e < end; e += 1024)
        atomicAdd(&lh[__builtin_nontemporal_load(dst + e) >> 8], 1);
    __syncthreads();
    for (int t = threadIdx.x; t < NB; t += 1024) gh[t * NBLK + g] = lh[t];
}

// ---------------------------------------------------------------------------
// Hierarchical exclusive scan of gh[GHLEN]
// ---------------------------------------------------------------------------
__global__ __launch_bounds__(1024) void scan1_kernel(
    int* __restrict__ gh, int* __restrict__ bsum)
{
    __shared__ int sbuf[1024];
    int tid = threadIdx.x;
    int t   = blockIdx.x * 1024 + tid;
    int v   = (t < GHLEN) ? gh[t] : 0;
    sbuf[tid] = v;
    __syncthreads();
    for (int d = 1; d < 1024; d <<= 1) {
        int u = (tid >= d) ? sbuf[tid - d] : 0;
        __syncthreads();
        sbuf[tid] += u;
        __syncthreads();
    }
    if (t < GHLEN) gh[t] = sbuf[tid] - v;           // local exclusive
    if (tid == 1023) bsum[blockIdx.x] = sbuf[1023]; // block total
}

__global__ __launch_bounds__(256) void scan2_kernel(int* __restrict__ bsum)
{
    __shared__ int sbuf[256];
    int tid = threadIdx.x;
    int v = (tid < SBLOCKS) ? bsum[tid] : 0;
    sbuf[tid] = v;
    __syncthreads();
    for (int d = 1; d < 256; d <<= 1) {
        int u = (tid >= d) ? sbuf[tid - d] : 0;
        __syncthreads();
        sbuf[tid] += u;
        __syncthreads();
    }
    if (tid < SBLOCKS) bsum[tid] = sbuf[tid] - v;   // exclusive
}

__global__ __launch_bounds__(1024) void scan3_kernel(
    int* __restrict__ gh, const int* __restrict__ bsum)
{
    int t = blockIdx.x * 1024 + threadIdx.x;
    if (t < GHLEN) gh[t] += bsum[blockIdx.x];
}

// ---------------------------------------------------------------------------
// Pass C, v2: counting-sort the whole chunk INSIDE LDS, then copy each
// (bucket,chunk) segment out as a contiguous per-wave burst.
//
// Why: v1 scattered 4 B stores across 200k open 128 B segments; L2 lines
// evicted partially written -> RMW at HBM (measured: 151 MB WRITE for a
// 25.6 MB payload, 5.9x amp; passC stuck at 105 us regardless of occupancy).
// Here consecutive lanes write consecutive addresses -> full lines, written
// once. Segment counts come free from the scanned gh (adjacent flat entries
// = same bucket, next chunk), so no histogram rebuild either.
// 116 KB dynamic LDS -> 1 block/CU (grid == 256 == CU count).
// ---------------------------------------------------------------------------
__global__ __launch_bounds__(1024) void passC_kernel(
    const int* __restrict__ src, const int* __restrict__ dst,
    const int* __restrict__ gh, int* __restrict__ ebuf)
{
    extern __shared__ int dyn[];
    int* earr = dyn;             // [CH]  bucket-sorted packed edges
    int* cnt  = dyn + CH;        // [NB]  edges of bucket b in this chunk
    int* ls   = cnt + NB;        // [NB]  local exclusive start
    int* lcur = ls + NB;         // [NB]  scatter cursor
    int* gs   = lcur + NB;       // [NB]  global segment start
    int* sbuf = gs + NB;         // [1024] scan temp

    int g   = blockIdx.x;
    int tid = threadIdx.x;

    // per-bucket global start + count for this chunk, from scanned gh
    for (int b = tid; b < NB; b += 1024) {
        int idx = b * NBLK + g;
        int s0  = gh[idx];
        int s1  = (idx + 1 < GHLEN) ? gh[idx + 1] : N_EDGES;
        gs[b]  = s0;
        cnt[b] = s1 - s0;
    }
    __syncthreads();

    // exclusive scan of cnt -> ls (NB=782 <= 1024, single pass)
    int v = (tid < NB) ? cnt[tid] : 0;
    sbuf[tid] = v;
    __syncthreads();
    for (int d = 1; d < 1024; d <<= 1) {
        int u = (tid >= d) ? sbuf[tid - d] : 0;
        __syncthreads();
        sbuf[tid] += u;
        __syncthreads();
    }
    if (tid < NB) { int e0 = sbuf[tid] - v; ls[tid] = e0; lcur[tid] = e0; }
    __syncthreads();

    // scatter chunk edges into LDS, bucket-grouped (LDS atomics only)
    int base = g * CH;
    for (int e = base + tid; e < base + CH; e += 1024) {
        int s = __builtin_nontemporal_load(src + e);
        int d = __builtin_nontemporal_load(dst + e);
        int b = d >> 8;
        int p = atomicAdd(&lcur[b], 1);
        earr[p] = (s << 8) | (d & 255);
    }
    __syncthreads();

    // coalesced copy-out: one wave per bucket segment (mean 32 edges = 128 B)
    int wv = tid >> 6, lane = tid & 63;
    for (int b = wv; b < NB; b += 16) {
        int bl = ls[b], bg = gs[b], c = cnt[b];
        for (int o = lane; o < c; o += 64)
            ebuf[bg + o] = earr[bl + o];   // normal store: L2 merges the
    }                                      // chunk-boundary-shared lines
}

// ---------------------------------------------------------------------------
// Pass D: per-bucket counting sort, IN PLACE (col aliases ebuf).
// ---------------------------------------------------------------------------
__global__ __launch_bounds__(256) void passD_kernel(
    const int* __restrict__ gh, int* __restrict__ col, int* __restrict__ off)
{
    __shared__ int earr[CAP];
    __shared__ int hist[256];
    __shared__ int incl[256];
    int b = blockIdx.x;
    int ebase = gh[b * NBLK];
    int eend  = (b == NB - 1) ? N_EDGES : gh[(b + 1) * NBLK];
    int n = eend - ebase;
    if (n > CAP) n = CAP;   // 68-sigma margin; never triggers for this input
    for (int k = threadIdx.x; k < n; k += 256)
        earr[k] = __builtin_nontemporal_load(col + ebase + k);
    hist[threadIdx.x] = 0;
    __syncthreads();
    for (int k = threadIdx.x; k < n; k += 256) atomicAdd(&hist[earr[k] & 255], 1);
    __syncthreads();
    int t = threadIdx.x;
    int h = hist[t];
    incl[t] = h;
    __syncthreads();
    for (int d = 1; d < 256; d <<= 1) {
        int v = (t >= d) ? incl[t - d] : 0;
        __syncthreads();
        incl[t] += v;
        __syncthreads();
    }
    int node = b * 256 + t;
    if (node < N_NODES) off[node] = ebase + incl[t];
    hist[t] = incl[t] - h;                       // exclusive cursor
    __syncthreads();
    for (int k = threadIdx.x; k < n; k += 256) {
        int e = earr[k];
        int p = atomicAdd(&hist[e & 255], 1);    // LDS atomic
        col[ebase + p] = e >> 8;                 // normal store (L2 coalesces)
    }
}

// ---------------------------------------------------------------------------
// round: v = in[i] + sum_{j in CSR(i)} in[col[j]]; rout[i] = sigmoid(v @ H)
// stored fp8 e4m3 (16 B rows -> 3.2 MB gather table).
// ---------------------------------------------------------------------------
template<int TD, bool FP8IN>
__device__ inline void accum_row(u32x4 q, float* v)
{
    if (FP8IN) {
        vf2 f0 = __builtin_amdgcn_cvt_pk_f32_fp8(q.x, false);
        vf2 f1 = __builtin_amdgcn_cvt_pk_f32_fp8(q.x, true);
        vf2 f2 = __builtin_amdgcn_cvt_pk_f32_fp8(q.y, false);
        vf2 f3 = __builtin_amdgcn_cvt_pk_f32_fp8(q.y, true);
        vf2 f4 = __builtin_amdgcn_cvt_pk_f32_fp8(q.z, false);
        v[0] += f0.x; v[1] += f0.y; v[2] += f1.x; v[3] += f1.y;
        v[4] += f2.x; v[5] += f2.y; v[6] += f3.x; v[7] += f3.y;
        v[8] += f4.x; v[9] += f4.y;
    } else {
        union { u32x4 q; __half2 h[8]; } u; u.q = q;
#pragma unroll
        for (int k = 0; k < TD / 2; ++k) {
            float2 f = __half22float2(u.h[k]);
            v[2 * k] += f.x; v[2 * k + 1] += f.y;
        }
    }
}

template<int TD, bool FP8IN>
__global__ __launch_bounds__(256) void round_kernel(
    const u32x4* __restrict__ in,      // [N] 16 B rows (fp16x8 or fp8x16)
    const int*   __restrict__ off,
    const int*   __restrict__ col,
    u32x4*       __restrict__ rout,    // [N] 16 B fp8 rows
    const float* __restrict__ H,       // [TD, M]
    const float* __restrict__ Wsc, int widx,
    float*       __restrict__ facc)
{
    int i = blockIdx.x * 256 + threadIdx.x;
    float w = Wsc[widx];
    float sm[M];

    if (i < N_NODES) {
        float v[TD];
#pragma unroll
        for (int t = 0; t < TD; ++t) v[t] = 0.0f;
        accum_row<TD, FP8IN>(in[i], v);
        int start = (i == 0) ? 0 : __builtin_nontemporal_load(off + i - 1);
        int end   = __builtin_nontemporal_load(off + i);

        int j = start;
        for (; j + 8 <= end; j += 8) {           // 8 outstanding gathers/lane
            int s0 = __builtin_nontemporal_load(col + j);
            int s1 = __builtin_nontemporal_load(col + j + 1);
            int s2 = __builtin_nontemporal_load(col + j + 2);
            int s3 = __builtin_nontemporal_load(col + j + 3);
            int s4 = __builtin_nontemporal_load(col + j + 4);
            int s5 = __builtin_nontemporal_load(col + j + 5);
            int s6 = __builtin_nontemporal_load(col + j + 6);
            int s7 = __builtin_nontemporal_load(col + j + 7);
            u32x4 q0 = in[s0], q1 = in[s1], q2 = in[s2], q3 = in[s3];
            u32x4 q4 = in[s4], q5 = in[s5], q6 = in[s6], q7 = in[s7];
            accum_row<TD, FP8IN>(q0, v);
            accum_row<TD, FP8IN>(q1, v);
            accum_row<TD, FP8IN>(q2, v);
            accum_row<TD, FP8IN>(q3, v);
            accum_row<TD, FP8IN>(q4, v);
            accum_row<TD, FP8IN>(q5, v);
            accum_row<TD, FP8IN>(q6, v);
            accum_row<TD, FP8IN>(q7, v);
        }
        for (; j + 4 <= end; j += 4) {
            int s0 = __builtin_nontemporal_load(col + j);
            int s1 = __builtin_nontemporal_load(col + j + 1);
            int s2 = __builtin_nontemporal_load(col + j + 2);
            int s3 = __builtin_nontemporal_load(col + j + 3);
            u32x4 q0 = in[s0], q1 = in[s1], q2 = in[s2], q3 = in[s3];
            accum_row<TD, FP8IN>(q0, v);
            accum_row<TD, FP8IN>(q1, v);
            accum_row<TD, FP8IN>(q2, v);
            accum_row<TD, FP8IN>(q3, v);
        }
        for (; j < end; ++j)
            accum_row<TD, FP8IN>(in[__builtin_nontemporal_load(col + j)], v);

        float z[M];
#pragma unroll
        for (int m = 0; m < M; ++m) {
            float acc = 0.0f;
#pragma unroll
            for (int t = 0; t < TD; ++t) acc += v[t] * H[t * M + m];
            z[m] = acc;
        }
        float rr[M];
        float ssum = 0.0f;
#pragma unroll
        for (int m = 0; m < M; ++m) {
            rr[m] = 1.0f / (1.0f + __expf(-z[m]));
            sm[m] = __expf(rr[m] * w);            // rr*w in (0,0.2): no max shift
            ssum += sm[m];
        }
        {
            int d0 = __builtin_amdgcn_cvt_pk_fp8_f32(rr[0], rr[1], 0, false);
            d0     = __builtin_amdgcn_cvt_pk_fp8_f32(rr[2], rr[3], d0, true);
            int d1 = __builtin_amdgcn_cvt_pk_fp8_f32(rr[4], rr[5], 0, false);
            d1     = __builtin_amdgcn_cvt_pk_fp8_f32(rr[6], rr[7], d1, true);
            int d2 = __builtin_amdgcn_cvt_pk_fp8_f32(rr[8], rr[9], 0, false);
            u32x4 o = { (unsigned)d0, (unsigned)d1, (unsigned)d2, 0u };
            __builtin_nontemporal_store(o, rout + i);
        }
        float inv = 1.0f / ssum;
#pragma unroll
        for (int m = 0; m < M; ++m) sm[m] *= inv;
    } else {
#pragma unroll
        for (int m = 0; m < M; ++m) sm[m] = 0.0f;
    }

    // wave-64 shuffle reduction of the 10 softmax sums
#pragma unroll
    for (int m = 0; m < M; ++m) {
        float x = sm[m];
#pragma unroll
        for (int o = 32; o > 0; o >>= 1) x += __shfl_down(x, o);
        sm[m] = x;
    }
    __shared__ float ls[4][M];
    int lane = threadIdx.x & 63;
    int wv   = threadIdx.x >> 6;
    if (lane == 0) {
#pragma unroll
        for (int m = 0; m < M; ++m) ls[wv][m] = sm[m];
    }
    __syncthreads();
    if (threadIdx.x < M) {
        float a = ls[0][threadIdx.x] + ls[1][threadIdx.x]
                + ls[2][threadIdx.x] + ls[3][threadIdx.x];
        atomicAdd(&facc[threadIdx.x], a);
    }
}

// ---------------------------------------------------------------------------
// final head: out[3] = concat(f[10], x_group@Wg[4]) @ Wm
// ---------------------------------------------------------------------------
__global__ void final_kernel(const float* __restrict__ facc,
                             const float* __restrict__ xg,
                             const float* __restrict__ Wg,
                             const float* __restrict__ Wm,
                             float* __restrict__ out)
{
    if (threadIdx.x == 0 && blockIdx.x == 0) {
        float go[4];
        for (int g = 0; g < 4; ++g) {
            float a = 0.0f;
            for (int i = 0; i < 14; ++i) a += xg[i] * Wg[i * 4 + g];
            go[g] = a;
        }
        for (int j = 0; j < 3; ++j) {
            float o = 0.0f;
            for (int k = 0; k < M; ++k) o += facc[k] * Wm[k * 3 + j];
            for (int g = 0; g < 4; ++g)  o += go[g] * Wm[(M + g) * 3 + j];
            out[j] = o;
        }
    }
}

extern "C" void kernel_launch(void* const* d_in, const int* in_sizes, int n_in,
                              void* d_out, int out_size, void* d_ws, size_t ws_size,
                              hipStream_t stream)
{
    const float* x_member = (const float*)d_in[0];
    const float* x_group  = (const float*)d_in[1];
    const int*   edge_src = (const int*)  d_in[2];
    const int*   edge_dst = (const int*)  d_in[3];
    const float* H0       = (const float*)d_in[4];
    const float* Hs       = (const float*)d_in[5];
    const float* Wsc      = (const float*)d_in[6];
    const float* Wg       = (const float*)d_in[7];
    const float* Wm       = (const float*)d_in[8];
    float* out = (float*)d_out;

    // workspace layout — 36.8 MB:
    //   col/ebuf : 25,600,000 B   (in-place counting sort)
    //   off      :    800,000 B
    //   xh       :  3,200,000 B   [N] fp16x8, 16 B rows
    //   r0b      :  3,200,000 B   [N] fp8x16, 16 B rows
    //   r1b      :  3,200,000 B   [N] fp8x16 (gh[GHLEN]+bsum alias its head:
    //              dead after passD; r1b first written in round 1)
    //   facc     :         64 B
    char* w = (char*)d_ws;
    int*    col  = (int*)w;
    int*    off  = (int*)(w + 25600000);
    __half* xh   = (__half*)(w + 26400000);
    u32x4*  r0b  = (u32x4*)(w + 29600000);
    u32x4*  r1b  = (u32x4*)(w + 32800000);
    int*    gh   = (int*)(w + 32800000);          // aliases r1b
    int*    bsum = gh + GHLEN;                    // also in r1b region
    float*  facc = (float*)(w + 36000000);

    // raise dynamic-LDS cap for passC (host-side attr, graph-capture safe)
    static bool attr_done = false;
    if (!attr_done) {
        (void)hipFuncSetAttribute((const void*)passC_kernel,
                                  hipFuncAttributeMaxDynamicSharedMemorySize,
                                  PASSC_LDS_BYTES);
        attr_done = true;
    }

    (void)hipMemsetAsync(facc, 0, 64, stream);

    const int nblocks = (N_NODES + 255) / 256;    // 782

    convert_kernel<<<nblocks, 256, 0, stream>>>(x_member, xh);
    passA_kernel<<<NBLK, 1024, 0, stream>>>(edge_dst, gh);
    scan1_kernel<<<SBLOCKS, 1024, 0, stream>>>(gh, bsum);
    scan2_kernel<<<1, 256, 0, stream>>>(bsum);
    scan3_kernel<<<SBLOCKS, 1024, 0, stream>>>(gh, bsum);
    passC_kernel<<<NBLK, 1024, PASSC_LDS_BYTES, stream>>>(edge_src, edge_dst, gh, col);
    passD_kernel<<<NB, 256, 0, stream>>>(gh, col, off);

    round_kernel<T, false><<<nblocks, 256, 0, stream>>>((const u32x4*)xh, off, col, r0b, H0,             Wsc, 0, facc);
    round_kernel<M, true ><<<nblocks, 256, 0, stream>>>(r0b,              off, col, r1b, Hs + 0 * M * M, Wsc, 1, facc);
    round_kernel<M, true ><<<nblocks, 256, 0, stream>>>(r1b,              off, col, r0b, Hs + 1 * M * M, Wsc, 2, facc);
    round_kernel<M, true ><<<nblocks, 256, 0, stream>>>(r0b,              off, col, r1b, Hs + 2 * M * M, Wsc, 3, facc);

    final_kernel<<<1, 64, 0, stream>>>(facc, x_group, Wg, Wm, out);
}

// Round 3
// 396.731 us; speedup vs baseline: 1.4427x; 1.1128x over previous
//
#include <hip/hip_runtime.h>
#include <hip/hip_fp16.h>
#include <math.h>

#define N_NODES 200000
#define N_EDGES 6400000
#define T 6
#define M 10

// CSR build configuration: 256-node buckets, chunked counting sort.
#define NB    782            // ceil(200000/256) buckets (dst>>8)
#define NBLK  256            // edge chunks == CU count
#define CH    25000          // edges per chunk (256*25000 = 6.4M exact)
#define GHLEN (NB * NBLK)    // 200192
#define CAP   14336          // max edges per bucket (mean 8186, sigma 90 -> 68 sigma margin)

#define SBLOCKS 196          // ceil(GHLEN/1024) scan blocks

// passC dynamic LDS: edge array (CH) + cnt/ls/lcur/gs (4*NB) + scan buf (1024)
#define PASSC_LDS_INTS  (CH + 4 * NB + 1024)
#define PASSC_LDS_BYTES (PASSC_LDS_INTS * 4)   // 116,608 B < 160 KiB/CU

// round kernel: staged col ints per bucket (36 KB). Bucket size is
// mean 8186, sigma 90 -> max over 782 buckets ~ 8490. 9216 = +11 sigma;
// a global-memory guard path covers the (never-seen) overflow case.
#define LCAP 9216

typedef __attribute__((ext_vector_type(2))) float vf2;
typedef __attribute__((ext_vector_type(4))) unsigned int u32x4;

// ---------------------------------------------------------------------------
// convert x_member [N,6] fp32 -> xh [N,8] fp16 (zero-padded), 16 B rows.
// ---------------------------------------------------------------------------
__global__ __launch_bounds__(256) void convert_kernel(
    const float* __restrict__ x, __half* __restrict__ xh)
{
    int i = blockIdx.x * 256 + threadIdx.x;
    if (i >= N_NODES) return;
    const vf2* p = (const vf2*)(x + (size_t)i * 6);   // rows 24B -> 8B aligned
    vf2 a = __builtin_nontemporal_load(p);
    vf2 b = __builtin_nontemporal_load(p + 1);
    vf2 c = __builtin_nontemporal_load(p + 2);
    union { __half2 h[4]; u32x4 q; } u;
    u.h[0] = __floats2half2_rn(a.x, a.y);
    u.h[1] = __floats2half2_rn(b.x, b.y);
    u.h[2] = __floats2half2_rn(c.x, c.y);
    u.h[3] = __floats2half2_rn(0.f, 0.f);
    __builtin_nontemporal_store(u.q, (u32x4*)(xh + (size_t)i * 8));
}

// ---------------------------------------------------------------------------
// Pass A: per-chunk bucket histogram -> gh[bucket*NBLK + chunk]
// ---------------------------------------------------------------------------
__global__ __launch_bounds__(1024) void passA_kernel(
    const int* __restrict__ dst, int* __restrict__ gh)
{
    __shared__ int lh[NB];
    int g = blockIdx.x;
    for (int t = threadIdx.x; t < NB; t += 1024) lh[t] = 0;
    __syncthreads();
    int base = g * CH;
    int end  = base + CH; if (end > N_EDGES) end = N_EDGES;
    for (int e = base + threadIdx.x; e < end; e += 1024)
        atomicAdd(&lh[__builtin_nontemporal_load(dst + e) >> 8], 1);
    __syncthreads();
    for (int t = threadIdx.x; t < NB; t += 1024) gh[t * NBLK + g] = lh[t];
}

// ---------------------------------------------------------------------------
// Hierarchical exclusive scan of gh[GHLEN]
// ---------------------------------------------------------------------------
__global__ __launch_bounds__(1024) void scan1_kernel(
    int* __restrict__ gh, int* __restrict__ bsum)
{
    __shared__ int sbuf[1024];
    int tid = threadIdx.x;
    int t   = blockIdx.x * 1024 + tid;
    int v   = (t < GHLEN) ? gh[t] : 0;
    sbuf[tid] = v;
    __syncthreads();
    for (int d = 1; d < 1024; d <<= 1) {
        int u = (tid >= d) ? sbuf[tid - d] : 0;
        __syncthreads();
        sbuf[tid] += u;
        __syncthreads();
    }
    if (t < GHLEN) gh[t] = sbuf[tid] - v;           // local exclusive
    if (tid == 1023) bsum[blockIdx.x] = sbuf[1023]; // block total
}

__global__ __launch_bounds__(256) void scan2_kernel(int* __restrict__ bsum)
{
    __shared__ int sbuf[256];
    int tid = threadIdx.x;
    int v = (tid < SBLOCKS) ? bsum[tid] : 0;
    sbuf[tid] = v;
    __syncthreads();
    for (int d = 1; d < 256; d <<= 1) {
        int u = (tid >= d) ? sbuf[tid - d] : 0;
        __syncthreads();
        sbuf[tid] += u;
        __syncthreads();
    }
    if (tid < SBLOCKS) bsum[tid] = sbuf[tid] - v;   // exclusive
}

__global__ __launch_bounds__(1024) void scan3_kernel(
    int* __restrict__ gh, const int* __restrict__ bsum)
{
    int t = blockIdx.x * 1024 + threadIdx.x;
    if (t < GHLEN) gh[t] += bsum[blockIdx.x];
}

// ---------------------------------------------------------------------------
// Pass C, v2: counting-sort the whole chunk INSIDE LDS, then copy each
// (bucket,chunk) segment out as a contiguous per-wave burst (full-line,
// write-once; v1's scattered 4 B stores cost 5.9x write amp at HBM).
// ---------------------------------------------------------------------------
__global__ __launch_bounds__(1024) void passC_kernel(
    const int* __restrict__ src, const int* __restrict__ dst,
    const int* __restrict__ gh, int* __restrict__ ebuf)
{
    extern __shared__ int dyn[];
    int* earr = dyn;             // [CH]  bucket-sorted packed edges
    int* cnt  = dyn + CH;        // [NB]  edges of bucket b in this chunk
    int* ls   = cnt + NB;        // [NB]  local exclusive start
    int* lcur = ls + NB;         // [NB]  scatter cursor
    int* gs   = lcur + NB;       // [NB]  global segment start
    int* sbuf = gs + NB;         // [1024] scan temp

    int g   = blockIdx.x;
    int tid = threadIdx.x;

    // per-bucket global start + count for this chunk, from scanned gh
    for (int b = tid; b < NB; b += 1024) {
        int idx = b * NBLK + g;
        int s0  = gh[idx];
        int s1  = (idx + 1 < GHLEN) ? gh[idx + 1] : N_EDGES;
        gs[b]  = s0;
        cnt[b] = s1 - s0;
    }
    __syncthreads();

    // exclusive scan of cnt -> ls (NB=782 <= 1024, single pass)
    int v = (tid < NB) ? cnt[tid] : 0;
    sbuf[tid] = v;
    __syncthreads();
    for (int d = 1; d < 1024; d <<= 1) {
        int u = (tid >= d) ? sbuf[tid - d] : 0;
        __syncthreads();
        sbuf[tid] += u;
        __syncthreads();
    }
    if (tid < NB) { int e0 = sbuf[tid] - v; ls[tid] = e0; lcur[tid] = e0; }
    __syncthreads();

    // scatter chunk edges into LDS, bucket-grouped (LDS atomics only)
    int base = g * CH;
    for (int e = base + tid; e < base + CH; e += 1024) {
        int s = __builtin_nontemporal_load(src + e);
        int d = __builtin_nontemporal_load(dst + e);
        int b = d >> 8;
        int p = atomicAdd(&lcur[b], 1);
        earr[p] = (s << 8) | (d & 255);
    }
    __syncthreads();

    // coalesced copy-out: one wave per bucket segment (mean 32 edges = 128 B)
    int wv = tid >> 6, lane = tid & 63;
    for (int b = wv; b < NB; b += 16) {
        int bl = ls[b], bg = gs[b], c = cnt[b];
        for (int o = lane; o < c; o += 64)
            ebuf[bg + o] = earr[bl + o];   // normal store: L2 merges the
    }                                      // chunk-boundary-shared lines
}

// ---------------------------------------------------------------------------
// Pass D: per-bucket counting sort, IN PLACE (col aliases ebuf).
// ---------------------------------------------------------------------------
__global__ __launch_bounds__(256) void passD_kernel(
    const int* __restrict__ gh, int* __restrict__ col, int* __restrict__ off)
{
    __shared__ int earr[CAP];
    __shared__ int hist[256];
    __shared__ int incl[256];
    int b = blockIdx.x;
    int ebase = gh[b * NBLK];
    int eend  = (b == NB - 1) ? N_EDGES : gh[(b + 1) * NBLK];
    int n = eend - ebase;
    if (n > CAP) n = CAP;   // 68-sigma margin; never triggers for this input
    for (int k = threadIdx.x; k < n; k += 256)
        earr[k] = __builtin_nontemporal_load(col + ebase + k);
    hist[threadIdx.x] = 0;
    __syncthreads();
    for (int k = threadIdx.x; k < n; k += 256) atomicAdd(&hist[earr[k] & 255], 1);
    __syncthreads();
    int t = threadIdx.x;
    int h = hist[t];
    incl[t] = h;
    __syncthreads();
    for (int d = 1; d < 256; d <<= 1) {
        int v = (t >= d) ? incl[t - d] : 0;
        __syncthreads();
        incl[t] += v;
        __syncthreads();
    }
    int node = b * 256 + t;
    if (node < N_NODES) off[node] = ebase + incl[t];
    hist[t] = incl[t] - h;                       // exclusive cursor
    __syncthreads();
    for (int k = threadIdx.x; k < n; k += 256) {
        int e = earr[k];
        int p = atomicAdd(&hist[e & 255], 1);    // LDS atomic
        col[ebase + p] = e >> 8;                 // normal store (L2 coalesces)
    }
}

// ---------------------------------------------------------------------------
// round, v2: block == bucket (256 nodes). The bucket's edge list is
// CONTIGUOUS in col (dst-sorted), so stage it into LDS with perfectly
// coalesced streaming loads, then walk segments from LDS.
//
// Why: v1's per-lane col walk was 64-way address-divergent -> every col
// read cost ~64 line-transactions at the TCP, doubling the unavoidable
// gather divergence (round stuck at 63 us, VALU 8%, HBM 15%, occ 24%).
// Staged col removes half the TCP serialization; gathers keep 8-deep MLP.
// LDS 37 KB -> grid 782 = 3 blocks/CU resident (12 waves), unchanged.
// ---------------------------------------------------------------------------
template<int TD, bool FP8IN>
__device__ inline void accum_row(u32x4 q, float* v)
{
    if (FP8IN) {
        vf2 f0 = __builtin_amdgcn_cvt_pk_f32_fp8(q.x, false);
        vf2 f1 = __builtin_amdgcn_cvt_pk_f32_fp8(q.x, true);
        vf2 f2 = __builtin_amdgcn_cvt_pk_f32_fp8(q.y, false);
        vf2 f3 = __builtin_amdgcn_cvt_pk_f32_fp8(q.y, true);
        vf2 f4 = __builtin_amdgcn_cvt_pk_f32_fp8(q.z, false);
        v[0] += f0.x; v[1] += f0.y; v[2] += f1.x; v[3] += f1.y;
        v[4] += f2.x; v[5] += f2.y; v[6] += f3.x; v[7] += f3.y;
        v[8] += f4.x; v[9] += f4.y;
    } else {
        union { u32x4 q; __half2 h[8]; } u; u.q = q;
#pragma unroll
        for (int k = 0; k < TD / 2; ++k) {
            float2 f = __half22float2(u.h[k]);
            v[2 * k] += f.x; v[2 * k + 1] += f.y;
        }
    }
}

template<int TD, bool FP8IN>
__global__ __launch_bounds__(256) void round_kernel(
    const u32x4* __restrict__ in,      // [N] 16 B rows (fp16x8 or fp8x16)
    const int*   __restrict__ off,
    const int*   __restrict__ col,
    u32x4*       __restrict__ rout,    // [N] 16 B fp8 rows
    const float* __restrict__ H,       // [TD, M]
    const float* __restrict__ Wsc, int widx,
    float*       __restrict__ facc)
{
    __shared__ int   lcol[LCAP];
    __shared__ int   shb[2];
    __shared__ float lsm[4][M];

    int b   = blockIdx.x;
    int tid = threadIdx.x;
    int i   = b * 256 + tid;

    if (tid == 0) {
        shb[0] = (b == 0) ? 0 : __builtin_nontemporal_load(off + b * 256 - 1);
        int lastnode = (b * 256 + 256 <= N_NODES) ? (b * 256 + 255) : (N_NODES - 1);
        shb[1] = __builtin_nontemporal_load(off + lastnode);
    }
    __syncthreads();
    int ebase  = shb[0];
    int nseg   = shb[1] - ebase;
    int nstage = nseg < LCAP ? nseg : LCAP;
    for (int k = tid; k < nstage; k += 256)
        lcol[k] = __builtin_nontemporal_load(col + ebase + k);   // coalesced
    __syncthreads();

    float w = Wsc[widx];
    float sm[M];

    if (i < N_NODES) {
        float v[TD];
#pragma unroll
        for (int t = 0; t < TD; ++t) v[t] = 0.0f;
        accum_row<TD, FP8IN>(in[i], v);
        int gstart = (i == 0) ? 0 : __builtin_nontemporal_load(off + i - 1);
        int gend   = __builtin_nontemporal_load(off + i);
        int js = gstart - ebase;
        int je = gend   - ebase;

        if (je <= nstage) {                      // fast path: col in LDS
            int j = js;
            for (; j + 8 <= je; j += 8) {        // 8 outstanding gathers/lane
                int s0 = lcol[j];
                int s1 = lcol[j + 1];
                int s2 = lcol[j + 2];
                int s3 = lcol[j + 3];
                int s4 = lcol[j + 4];
                int s5 = lcol[j + 5];
                int s6 = lcol[j + 6];
                int s7 = lcol[j + 7];
                u32x4 q0 = in[s0], q1 = in[s1], q2 = in[s2], q3 = in[s3];
                u32x4 q4 = in[s4], q5 = in[s5], q6 = in[s6], q7 = in[s7];
                accum_row<TD, FP8IN>(q0, v);
                accum_row<TD, FP8IN>(q1, v);
                accum_row<TD, FP8IN>(q2, v);
                accum_row<TD, FP8IN>(q3, v);
                accum_row<TD, FP8IN>(q4, v);
                accum_row<TD, FP8IN>(q5, v);
                accum_row<TD, FP8IN>(q6, v);
                accum_row<TD, FP8IN>(q7, v);
            }
            for (; j < je; ++j)
                accum_row<TD, FP8IN>(in[lcol[j]], v);
        } else {                                 // overflow guard (never hit)
            for (int j = gstart; j < gend; ++j)
                accum_row<TD, FP8IN>(in[__builtin_nontemporal_load(col + j)], v);
        }

        float z[M];
#pragma unroll
        for (int m = 0; m < M; ++m) {
            float acc = 0.0f;
#pragma unroll
            for (int t = 0; t < TD; ++t) acc += v[t] * H[t * M + m];
            z[m] = acc;
        }
        float rr[M];
        float ssum = 0.0f;
#pragma unroll
        for (int m = 0; m < M; ++m) {
            rr[m] = 1.0f / (1.0f + __expf(-z[m]));
            sm[m] = __expf(rr[m] * w);            // rr*w in (0,0.2): no max shift
            ssum += sm[m];
        }
        {
            int d0 = __builtin_amdgcn_cvt_pk_fp8_f32(rr[0], rr[1], 0, false);
            d0     = __builtin_amdgcn_cvt_pk_fp8_f32(rr[2], rr[3], d0, true);
            int d1 = __builtin_amdgcn_cvt_pk_fp8_f32(rr[4], rr[5], 0, false);
            d1     = __builtin_amdgcn_cvt_pk_fp8_f32(rr[6], rr[7], d1, true);
            int d2 = __builtin_amdgcn_cvt_pk_fp8_f32(rr[8], rr[9], 0, false);
            u32x4 o = { (unsigned)d0, (unsigned)d1, (unsigned)d2, 0u };
            __builtin_nontemporal_store(o, rout + i);
        }
        float inv = 1.0f / ssum;
#pragma unroll
        for (int m = 0; m < M; ++m) sm[m] *= inv;
    } else {
#pragma unroll
        for (int m = 0; m < M; ++m) sm[m] = 0.0f;
    }

    // wave-64 shuffle reduction of the 10 softmax sums
#pragma unroll
    for (int m = 0; m < M; ++m) {
        float x = sm[m];
#pragma unroll
        for (int o = 32; o > 0; o >>= 1) x += __shfl_down(x, o);
        sm[m] = x;
    }
    int lane = threadIdx.x & 63;
    int wv   = threadIdx.x >> 6;
    if (lane == 0) {
#pragma unroll
        for (int m = 0; m < M; ++m) lsm[wv][m] = sm[m];
    }
    __syncthreads();
    if (threadIdx.x < M) {
        float a = lsm[0][threadIdx.x] + lsm[1][threadIdx.x]
                + lsm[2][threadIdx.x] + lsm[3][threadIdx.x];
        atomicAdd(&facc[threadIdx.x], a);
    }
}

// ---------------------------------------------------------------------------
// final head: out[3] = concat(f[10], x_group@Wg[4]) @ Wm
// ---------------------------------------------------------------------------
__global__ void final_kernel(const float* __restrict__ facc,
                             const float* __restrict__ xg,
                             const float* __restrict__ Wg,
                             const float* __restrict__ Wm,
                             float* __restrict__ out)
{
    if (threadIdx.x == 0 && blockIdx.x == 0) {
        float go[4];
        for (int g = 0; g < 4; ++g) {
            float a = 0.0f;
            for (int i = 0; i < 14; ++i) a += xg[i] * Wg[i * 4 + g];
            go[g] = a;
        }
        for (int j = 0; j < 3; ++j) {
            float o = 0.0f;
            for (int k = 0; k < M; ++k) o += facc[k] * Wm[k * 3 + j];
            for (int g = 0; g < 4; ++g)  o += go[g] * Wm[(M + g) * 3 + j];
            out[j] = o;
        }
    }
}

extern "C" void kernel_launch(void* const* d_in, const int* in_sizes, int n_in,
                              void* d_out, int out_size, void* d_ws, size_t ws_size,
                              hipStream_t stream)
{
    const float* x_member = (const float*)d_in[0];
    const float* x_group  = (const float*)d_in[1];
    const int*   edge_src = (const int*)  d_in[2];
    const int*   edge_dst = (const int*)  d_in[3];
    const float* H0       = (const float*)d_in[4];
    const float* Hs       = (const float*)d_in[5];
    const float* Wsc      = (const float*)d_in[6];
    const float* Wg       = (const float*)d_in[7];
    const float* Wm       = (const float*)d_in[8];
    float* out = (float*)d_out;

    // workspace layout — 36.8 MB:
    //   col/ebuf : 25,600,000 B   (in-place counting sort)
    //   off      :    800,000 B
    //   xh       :  3,200,000 B   [N] fp16x8, 16 B rows
    //   r0b      :  3,200,000 B   [N] fp8x16, 16 B rows
    //   r1b      :  3,200,000 B   [N] fp8x16 (gh[GHLEN]+bsum alias its head:
    //              dead after passD; r1b first written in round 1)
    //   facc     :         64 B
    char* w = (char*)d_ws;
    int*    col  = (int*)w;
    int*    off  = (int*)(w + 25600000);
    __half* xh   = (__half*)(w + 26400000);
    u32x4*  r0b  = (u32x4*)(w + 29600000);
    u32x4*  r1b  = (u32x4*)(w + 32800000);
    int*    gh   = (int*)(w + 32800000);          // aliases r1b
    int*    bsum = gh + GHLEN;                    // also in r1b region
    float*  facc = (float*)(w + 36000000);

    // raise dynamic-LDS cap for passC (host-side attr, graph-capture safe)
    static bool attr_done = false;
    if (!attr_done) {
        (void)hipFuncSetAttribute((const void*)passC_kernel,
                                  hipFuncAttributeMaxDynamicSharedMemorySize,
                                  PASSC_LDS_BYTES);
        attr_done = true;
    }

    (void)hipMemsetAsync(facc, 0, 64, stream);

    const int nblocks = (N_NODES + 255) / 256;    // 782

    convert_kernel<<<nblocks, 256, 0, stream>>>(x_member, xh);
    passA_kernel<<<NBLK, 1024, 0, stream>>>(edge_dst, gh);
    scan1_kernel<<<SBLOCKS, 1024, 0, stream>>>(gh, bsum);
    scan2_kernel<<<1, 256, 0, stream>>>(bsum);
    scan3_kernel<<<SBLOCKS, 1024, 0, stream>>>(gh, bsum);
    passC_kernel<<<NBLK, 1024, PASSC_LDS_BYTES, stream>>>(edge_src, edge_dst, gh, col);
    passD_kernel<<<NB, 256, 0, stream>>>(gh, col, off);

    round_kernel<T, false><<<nblocks, 256, 0, stream>>>((const u32x4*)xh, off, col, r0b, H0,             Wsc, 0, facc);
    round_kernel<M, true ><<<nblocks, 256, 0, stream>>>(r0b,              off, col, r1b, Hs + 0 * M * M, Wsc, 1, facc);
    round_kernel<M, true ><<<nblocks, 256, 0, stream>>>(r1b,              off, col, r0b, Hs + 1 * M * M, Wsc, 2, facc);
    round_kernel<M, true ><<<nblocks, 256, 0, stream>>>(r0b,              off, col, r1b, Hs + 2 * M * M, Wsc, 3, facc);

    final_kernel<<<1, 64, 0, stream>>>(facc, x_group, Wg, Wm, out);
}